// Round 5
// baseline (77.134 us; speedup 1.0000x reference)
//
#include <hip/hip_runtime.h>

#define BATCH 4
#define NH    8
#define SEQ   2048
#define HDIM  64
#define DIN   512
#define DCAT  512
#define NBH   (BATCH*NH)   // 32
#define NT    32           // kv tiles per half (32 rows each -> 1024 kv per half)

typedef __attribute__((ext_vector_type(8))) short short8;
typedef __attribute__((ext_vector_type(4))) float f32x4;
typedef __attribute__((ext_vector_type(16))) float f32x16;
typedef __attribute__((ext_vector_type(4))) unsigned int uint4v;
typedef __attribute__((ext_vector_type(2))) unsigned int uint2v;
typedef unsigned short u16;
typedef unsigned int u32;

#define ZERO16 (f32x16){0.f,0.f,0.f,0.f,0.f,0.f,0.f,0.f,0.f,0.f,0.f,0.f,0.f,0.f,0.f,0.f}

__device__ inline u32 cvtpk(float lo, float hi) {
    u32 r;
    asm("v_cvt_pk_bf16_f32 %0, %1, %2" : "=v"(r) : "v"(lo), "v"(hi));
    return r;
}

__device__ inline void glds16(const void* g, void* l) {
    __builtin_amdgcn_global_load_lds(
        (const __attribute__((address_space(1))) u32*)g,
        (__attribute__((address_space(3))) u32*)l, 16, 0, 0);
}

// ---------- prepass: V [bh][s][d] fp32 -> V^T bf16 tiles, per (bh, t of 32 kv):
// [32 rows][8 slots x 16B]; row r holds d=r (kv 0..31) then d=r+32 (kv 0..31);
// physical slot p of row r stores logical slot (p ^ (r&7))  (pre-swizzled for glds)
__global__ __launch_bounds__(256)
void vt_prepass(const float* __restrict__ vg, u16* __restrict__ vt) {
    const int bh = blockIdx.x, tb = blockIdx.y, t = threadIdx.x;
    __shared__ float Ls[32][65];
    const float* vp = vg + ((size_t)bh * SEQ + tb * 32) * HDIM;
    {
        int r = t >> 3, c8 = (t & 7) * 8;
        float4 f0 = *reinterpret_cast<const float4*>(vp + r * HDIM + c8);
        float4 f1 = *reinterpret_cast<const float4*>(vp + r * HDIM + c8 + 4);
        Ls[r][c8+0] = f0.x; Ls[r][c8+1] = f0.y; Ls[r][c8+2] = f0.z; Ls[r][c8+3] = f0.w;
        Ls[r][c8+4] = f1.x; Ls[r][c8+5] = f1.y; Ls[r][c8+6] = f1.z; Ls[r][c8+7] = f1.w;
    }
    __syncthreads();
    u16* wt = vt + ((size_t)bh * 64 + tb) * 2048;
    {
        int r = t >> 3, p = t & 7;
        int sL = p ^ (r & 7);
        int d  = (sL >> 2) * 32 + r;
        int j0 = (sL & 3) * 8;
        uint4v u;
        u.x = cvtpk(Ls[j0+0][d], Ls[j0+1][d]);
        u.y = cvtpk(Ls[j0+2][d], Ls[j0+3][d]);
        u.z = cvtpk(Ls[j0+4][d], Ls[j0+5][d]);
        u.w = cvtpk(Ls[j0+6][d], Ls[j0+7][d]);
        *reinterpret_cast<uint4v*>(wt + r * 64 + p * 8) = u;
    }
}

// ---------- flash attention: 32x32x16 MFMA, P in registers, 8 waves =
// 4 q-chunks (32 q) x 2 KV-halves, kv-tile 32, unnormalized exp2 softmax ----------
__global__ __launch_bounds__(512, 4)
void attn_mfma(const float* __restrict__ qg, const float* __restrict__ kg,
               const u16* __restrict__ vtg, u16* __restrict__ og) {
    const int bh  = blockIdx.x;
    const int qB  = blockIdx.y * 128;
    const int tid = threadIdx.x;
    const int w = tid >> 6, lane = tid & 63;
    const int qc = w & 3, half = w >> 2;
    const int r  = lane & 31;          // MFMA A-row / C-col
    const int hi = lane >> 5;          // k-half
    const bool hib = hi != 0;

    __shared__ char sh[33792];   // K 16K | V 16K | l 1K  (K/V reused by epilogue)
    auto Kb = [&](int h, int b) { return sh + (h*2 + b) * 4096; };
    auto Vb = [&](int h, int b) { return sh + 16384 + (h*2 + b) * 4096; };

    const size_t base = (size_t)bh * SEQ * HDIM;

    // Q B-fragments (col q = r, k = ks*16 + hi*8 + i), pre-scaled by 0.125*log2e
    const float qs = 0.125f * 1.44269504088896f;
    short8 qb[4];
#pragma unroll
    for (int ks = 0; ks < 4; ++ks) {
        const float* qp = qg + base + (size_t)(qB + qc*32 + r) * HDIM + ks*16 + hi*8;
        float4 f0 = *reinterpret_cast<const float4*>(qp);
        float4 f1 = *reinterpret_cast<const float4*>(qp + 4);
        uint4v u;
        u.x = cvtpk(f0.x * qs, f0.y * qs);
        u.y = cvtpk(f0.z * qs, f0.w * qs);
        u.z = cvtpk(f1.x * qs, f1.y * qs);
        u.w = cvtpk(f1.z * qs, f1.w * qs);
        qb[ks] = __builtin_bit_cast(short8, u);
    }

    // staging geometry (block stages BOTH halves' tiles)
    const int srow = tid >> 4;                 // 0..31  K tile row
    const int sp4  = tid & 15;                 // 4-float chunk
    const int kwoff = srow*128 + ((((sp4 >> 1) ^ (srow & 7)) << 4) | ((sp4 & 1) << 3));
    const float* kgp0 = kg + base + (size_t)srow * HDIM + sp4 * 4;   // half 0
    const float* kgp1 = kgp0 + (size_t)1024 * HDIM;                   // half 1
    const int vh  = tid >> 8;                  // V staging half
    const int vls = (tid & 255) * 16;          // V LDS byte offset (linear)
    const u16* vsrc = vtg + (size_t)bh * 64 * 2048 + (size_t)(vh * 32) * 2048 + (tid & 255) * 8;

    f32x16 ot[2] = { ZERO16, ZERO16 };
    float l = 0.f;

    float4 kr0, kr1;
    // ---- prologue ----
    kr0 = *reinterpret_cast<const float4*>(kgp0);
    kr1 = *reinterpret_cast<const float4*>(kgp1);
    glds16(vsrc, Vb(vh, 0) + vls);
    {
        uint2v u0, u1;
        u0.x = cvtpk(kr0.x, kr0.y); u0.y = cvtpk(kr0.z, kr0.w);
        u1.x = cvtpk(kr1.x, kr1.y); u1.y = cvtpk(kr1.z, kr1.w);
        *reinterpret_cast<uint2v*>(Kb(0,0) + kwoff) = u0;
        *reinterpret_cast<uint2v*>(Kb(1,0) + kwoff) = u1;
    }
    kr0 = *reinterpret_cast<const float4*>(kgp0 + 2048);
    kr1 = *reinterpret_cast<const float4*>(kgp1 + 2048);
    asm volatile("s_waitcnt vmcnt(2) lgkmcnt(0)" ::: "memory");
    __builtin_amdgcn_s_barrier();
    glds16(vsrc + 2048, Vb(vh, 1) + vls);

    for (int t = 0; t < NT; ++t) {
        const int b = t & 1;
        const char* Kc = Kb(half, b);
        const char* Vc = Vb(half, b);

        // ---- QK^T (swapped): S^T[kv][q] = K * Q^T, one 32x32 tile ----
        f32x16 st = ZERO16;
        __builtin_amdgcn_s_setprio(1);
#pragma unroll
        for (int ks = 0; ks < 4; ++ks) {
            short8 ka = *reinterpret_cast<const short8*>(
                Kc + r*128 + (((ks*2 + hi) ^ (r & 7)) << 4));
            st = __builtin_amdgcn_mfma_f32_32x32x16_bf16(ka, qb[ks], st, 0, 0, 0);
        }
        __builtin_amdgcn_s_setprio(0);

        // ---- unnormalized softmax: p = exp2(s); pack to bf16 words ----
        u32 pw[8];
        float lp = 0.f;
#pragma unroll
        for (int j = 0; j < 8; ++j) {
            float p0 = __builtin_amdgcn_exp2f(st[2*j]);
            float p1 = __builtin_amdgcn_exp2f(st[2*j+1]);
            lp += p0 + p1;
            pw[j] = cvtpk(p0, p1);
        }
        l += lp;

        // exchange halves: lane <-> lane^32 (same q column)
        u32 xw[8];
#pragma unroll
        for (int j = 0; j < 8; ++j) xw[j] = (u32)__shfl_xor((int)pw[j], 32);

        // assemble P^T B-fragments (k = kv = ks*16 + hi*8 + i)
        uint4v b0, b1;
        b0.x = hib ? xw[2] : pw[0];  b0.y = hib ? xw[3] : pw[1];
        b0.z = hib ? pw[2] : xw[0];  b0.w = hib ? pw[3] : xw[1];
        b1.x = hib ? xw[6] : pw[4];  b1.y = hib ? xw[7] : pw[5];
        b1.z = hib ? pw[6] : xw[4];  b1.w = hib ? pw[7] : xw[5];
        short8 pb[2] = { __builtin_bit_cast(short8, b0), __builtin_bit_cast(short8, b1) };

        // ---- PV (swapped): O^T[d][q] += V^T[d][kv] * P^T[kv][q] ----
        __builtin_amdgcn_s_setprio(1);
#pragma unroll
        for (int dt = 0; dt < 2; ++dt)
#pragma unroll
        for (int ks = 0; ks < 2; ++ks) {
            short8 va = *reinterpret_cast<const short8*>(
                Vc + r*128 + (((dt*4 + ks*2 + hi) ^ (r & 7)) << 4));
            ot[dt] = __builtin_amdgcn_mfma_f32_32x32x16_bf16(va, pb[ks], ot[dt], 0, 0, 0);
        }
        __builtin_amdgcn_s_setprio(0);

        // ---- bottom: write K(t+1), prefetch K(t+2), counted fence, barrier, issue V(t+2) ----
        if (t + 1 < NT) {
            uint2v u0, u1;
            u0.x = cvtpk(kr0.x, kr0.y); u0.y = cvtpk(kr0.z, kr0.w);
            u1.x = cvtpk(kr1.x, kr1.y); u1.y = cvtpk(kr1.z, kr1.w);
            *reinterpret_cast<uint2v*>(Kb(0, b ^ 1) + kwoff) = u0;
            *reinterpret_cast<uint2v*>(Kb(1, b ^ 1) + kwoff) = u1;
        }
        if (t + 2 < NT) {
            kr0 = *reinterpret_cast<const float4*>(kgp0 + (size_t)(t + 2) * 2048);
            kr1 = *reinterpret_cast<const float4*>(kgp1 + (size_t)(t + 2) * 2048);
        }
        if (t < NT - 2)
            asm volatile("s_waitcnt vmcnt(2) lgkmcnt(0)" ::: "memory");
        else
            asm volatile("s_waitcnt vmcnt(0) lgkmcnt(0)" ::: "memory");
        __builtin_amdgcn_s_barrier();
        if (t + 2 < NT)
            glds16(vsrc + (size_t)(t + 2) * 2048, Vb(vh, b) + vls);
    }

    // ---- epilogue: combine halves, normalize, transpose, coalesced bf16 store ----
    l += __shfl_xor(l, 32);                 // wave-total l for q = r

    float* dumpF = (float*)(sh + (w & 3) * 8192) + lane * 32;
    float* dumpL = (float*)(sh + 32768) + (w & 3) * 64;
    if (w >= 4) {
#pragma unroll
        for (int dt = 0; dt < 2; ++dt)
#pragma unroll
        for (int jj = 0; jj < 4; ++jj) {
            f32x4 c = { ot[dt][jj*4+0], ot[dt][jj*4+1], ot[dt][jj*4+2], ot[dt][jj*4+3] };
            *reinterpret_cast<f32x4*>(dumpF + dt*16 + jj*4) = c;
        }
        dumpL[lane] = l;
    }
    __syncthreads();
    if (w < 4) {
#pragma unroll
        for (int dt = 0; dt < 2; ++dt)
#pragma unroll
        for (int jj = 0; jj < 4; ++jj) {
            f32x4 c = *reinterpret_cast<const f32x4*>(dumpF + dt*16 + jj*4);
            ot[dt][jj*4+0] += c[0]; ot[dt][jj*4+1] += c[1];
            ot[dt][jj*4+2] += c[2]; ot[dt][jj*4+3] += c[3];
        }
        float ltot = l + dumpL[lane];
        float inv  = 1.0f / ltot;
        asm volatile("s_waitcnt lgkmcnt(0)" ::: "memory");
        __builtin_amdgcn_sched_barrier(0);
        // pack + transposed write into own area: row q = r, 72 u16 per row
        u16* ta = (u16*)(sh + w * 8192);
#pragma unroll
        for (int dt = 0; dt < 2; ++dt)
#pragma unroll
        for (int j = 0; j < 8; ++j) {
            u32 wd = cvtpk(ot[dt][2*j] * inv, ot[dt][2*j+1] * inv);
            int d = dt*32 + ((2*j) & 3) + 8*((2*j) >> 2) + 4*hi;
            *reinterpret_cast<u32*>((char*)ta + r*144 + d*2) = wd;
        }
        asm volatile("s_waitcnt lgkmcnt(0)" ::: "memory");
        __builtin_amdgcn_sched_barrier(0);
#pragma unroll
        for (int s = 0; s < 4; ++s) {
            int idx = lane + s*64;
            int rr = idx >> 3, j = idx & 7;
            uint4v u = *reinterpret_cast<const uint4v*>((char*)ta + rr*144 + j*16);
            *reinterpret_cast<uint4v*>(
                og + ((size_t)bh * SEQ + qB + w*32 + rr) * HDIM + j*8) = u;
        }
    }
}

// ---------- projection: C = X(bf16) @ W^T + bias via MFMA ----------
__global__ __launch_bounds__(256)
void proj_mfma(const u16* __restrict__ X, const float* __restrict__ Wg,
               const float* __restrict__ bias, float* __restrict__ out) {
    const int g0 = blockIdx.x * 128;
    const int n0 = blockIdx.y * 64;
    const int tid = threadIdx.x;
    const int w = tid >> 6, lane = tid & 63;
    const int c = lane & 15, gq = lane >> 4;
    const int cx = c & 7;

    __shared__ char sh[49152];                 // X dbuf 32K + W dbuf 16K
    u16* const XbA = (u16*)(sh);
    u16* const XbB = (u16*)(sh + 16384);
    u16* const WbA = (u16*)(sh + 32768);
    u16* const WbB = (u16*)(sh + 40960);

    const int wn0 = tid >> 3, wp = tid & 7;

    f32x4 acc[2][4];
#pragma unroll
    for (int mt = 0; mt < 2; ++mt)
#pragma unroll
    for (int nt = 0; nt < 4; ++nt) acc[mt][nt] = (f32x4){0.f,0.f,0.f,0.f};

    float4 w0a, w0b, w1a, w1b;

    auto loadW = [&](int kt) {
        const float* p0 = Wg + (size_t)(n0 + wn0) * DCAT + kt*64 + ((wp ^ (wn0 & 7)) * 8);
        const float* p1 = Wg + (size_t)(n0 + 32 + wn0) * DCAT + kt*64 + ((wp ^ ((32 + wn0) & 7)) * 8);
        w0a = *reinterpret_cast<const float4*>(p0);
        w0b = *reinterpret_cast<const float4*>(p0 + 4);
        w1a = *reinterpret_cast<const float4*>(p1);
        w1b = *reinterpret_cast<const float4*>(p1 + 4);
    };
    auto writeW = [&](u16* Wb) {
        uint4v u;
        u.x = cvtpk(w0a.x, w0a.y); u.y = cvtpk(w0a.z, w0a.w);
        u.z = cvtpk(w0b.x, w0b.y); u.w = cvtpk(w0b.z, w0b.w);
        *reinterpret_cast<uint4v*>((char*)Wb + wn0*128 + wp*16) = u;
        u.x = cvtpk(w1a.x, w1a.y); u.y = cvtpk(w1a.z, w1a.w);
        u.z = cvtpk(w1b.x, w1b.y); u.w = cvtpk(w1b.z, w1b.w);
        *reinterpret_cast<uint4v*>((char*)Wb + (32 + wn0)*128 + wp*16) = u;
    };
    auto issueX = [&](int kt, u16* Xb) {
#pragma unroll
        for (int i = 0; i < 4; ++i) {
            int s = w*256 + i*64 + lane;
            int rr = s >> 3, p = s & 7;
            glds16(X + (size_t)(g0 + rr) * DCAT + kt*64 + ((p ^ (rr & 7)) * 8),
                   (char*)Xb + w*4096 + i*1024);
        }
    };

    loadW(0);
    issueX(0, XbA);
    writeW(WbA);
    loadW(1);
    issueX(1, XbB);
    asm volatile("s_waitcnt vmcnt(8) lgkmcnt(0)" ::: "memory");
    __builtin_amdgcn_s_barrier();

    for (int kt = 0; kt < 8; ++kt) {
        u16* const Xc = (kt & 1) ? XbB : XbA;
        u16* const Wc = (kt & 1) ? WbB : WbA;
        u16* const Wn = (kt & 1) ? WbA : WbB;

        __builtin_amdgcn_s_setprio(1);
#pragma unroll
        for (int ks = 0; ks < 2; ++ks) {
            short8 a0 = *reinterpret_cast<const short8*>(
                (char*)Xc + (w*32 + c)*128 + (((ks*4 + gq) ^ cx) << 4));
            short8 a1 = *reinterpret_cast<const short8*>(
                (char*)Xc + (w*32 + 16 + c)*128 + (((ks*4 + gq) ^ cx) << 4));
#pragma unroll
            for (int nt = 0; nt < 4; ++nt) {
                short8 bb = *reinterpret_cast<const short8*>(
                    (char*)Wc + (nt*16 + c)*128 + (((ks*4 + gq) ^ cx) << 4));
                acc[0][nt] = __builtin_amdgcn_mfma_f32_16x16x32_bf16(a0, bb, acc[0][nt], 0,0,0);
                acc[1][nt] = __builtin_amdgcn_mfma_f32_16x16x32_bf16(a1, bb, acc[1][nt], 0,0,0);
            }
        }
        __builtin_amdgcn_s_setprio(0);

        if (kt + 1 < 8) writeW(Wn);
        if (kt + 2 < 8) loadW(kt + 2);
        if (kt < 6)
            asm volatile("s_waitcnt vmcnt(4) lgkmcnt(0)" ::: "memory");
        else
            asm volatile("s_waitcnt vmcnt(0) lgkmcnt(0)" ::: "memory");
        __builtin_amdgcn_s_barrier();
        if (kt + 2 < 8) issueX(kt + 2, Xc);
    }

    float bv[4];
#pragma unroll
    for (int nt = 0; nt < 4; ++nt) bv[nt] = bias[n0 + nt*16 + c];
#pragma unroll
    for (int mt = 0; mt < 2; ++mt)
#pragma unroll
    for (int nt = 0; nt < 4; ++nt)
#pragma unroll
    for (int rr = 0; rr < 4; ++rr)
        out[(size_t)(g0 + w*32 + mt*16 + gq*4 + rr) * DIN + n0 + nt*16 + c] =
            acc[mt][nt][rr] + bv[nt];
}

extern "C" void kernel_launch(void* const* d_in, const int* in_sizes, int n_in,
                              void* d_out, int out_size, void* d_ws, size_t ws_size,
                              hipStream_t stream) {
    (void)in_sizes; (void)n_in; (void)out_size; (void)ws_size;
    const float* q    = (const float*)d_in[0];
    const float* k    = (const float*)d_in[1];
    const float* v    = (const float*)d_in[2];
    const float* W    = (const float*)d_in[3];
    const float* bias = (const float*)d_in[4];

    u16* vt = (u16*)d_ws;                              // V^T bf16 tiled: 8 MB
    u16* ob = vt + (size_t)NBH * 64 * 2048;            // O bf16:        8 MB

    vt_prepass<<<dim3(NBH, 64), 256, 0, stream>>>(v, vt);
    attn_mfma <<<dim3(NBH, SEQ/128), 512, 0, stream>>>(q, k, vt, ob);
    proj_mfma <<<dim3((BATCH*SEQ)/128, DIN/64), 256, 0, stream>>>(ob, W, bias, (float*)d_out);
}

// Round 6
// 69.529 us; speedup vs baseline: 1.1094x; 1.1094x over previous
//
#include <hip/hip_runtime.h>

#define BATCH 4
#define NH    8
#define SEQ   2048
#define HDIM  64
#define DIN   512
#define DCAT  512
#define NBH   (BATCH*NH)   // 32
#define NT    32           // kv tiles per half (32 rows each -> 1024 kv per half)

typedef __attribute__((ext_vector_type(8))) short short8;
typedef __attribute__((ext_vector_type(4))) float f32x4;
typedef __attribute__((ext_vector_type(16))) float f32x16;
typedef __attribute__((ext_vector_type(4))) unsigned int uint4v;
typedef unsigned short u16;
typedef unsigned int u32;

#define ZERO16 (f32x16){0.f,0.f,0.f,0.f,0.f,0.f,0.f,0.f,0.f,0.f,0.f,0.f,0.f,0.f,0.f,0.f}

__device__ inline u32 cvtpk(float lo, float hi) {
    u32 r;
    asm("v_cvt_pk_bf16_f32 %0, %1, %2" : "=v"(r) : "v"(lo), "v"(hi));
    return r;
}

// in-place half-swap: a' = [a_lo | b_lo], b' = [a_hi | b_hi]
__device__ inline void plswap(u32 &a, u32 &b) {
    asm volatile("v_permlane32_swap_b32 %0, %1" : "+v"(a), "+v"(b));
}

__device__ inline void glds16(const void* g, void* l) {
    __builtin_amdgcn_global_load_lds(
        (const __attribute__((address_space(1))) u32*)g,
        (__attribute__((address_space(3))) u32*)l, 16, 0, 0);
}

// ---------- prepass: K and V fp32 -> bf16 glds-ready tiles of 32 kv rows ----------
// K tile [bh][tb]: row srow (32) x 8 slots of 16B; physical slot p holds d-chunk (p^(srow&7)).
// V tile [bh][tb]: row r x 8 slots; logical slot sL=(p^(r&7)): d=(sL>>2)*32+r, kv-chunk (sL&3)*8.
__global__ __launch_bounds__(256)
void kv_prepass(const float* __restrict__ kg, const float* __restrict__ vg,
                u16* __restrict__ kws, u16* __restrict__ vws) {
    const int tb = blockIdx.x;   // 0..63
    const int bh = blockIdx.y;   // 0..31
    const int t  = threadIdx.x;
    const size_t gbase = ((size_t)bh * SEQ + tb * 32) * HDIM;

    {   // K: direct swizzled convert
        int srow = t >> 3, j = t & 7;
        const float* kp = kg + gbase + srow * HDIM + j * 8;
        float4 f0 = *reinterpret_cast<const float4*>(kp);
        float4 f1 = *reinterpret_cast<const float4*>(kp + 4);
        uint4v u;
        u.x = cvtpk(f0.x, f0.y); u.y = cvtpk(f0.z, f0.w);
        u.z = cvtpk(f1.x, f1.y); u.w = cvtpk(f1.z, f1.w);
        *reinterpret_cast<uint4v*>(kws + ((size_t)bh*64 + tb)*2048 + srow*64 + (j ^ (srow & 7))*8) = u;
    }

    __shared__ float Ls[32][65];
    {   // V: load rows
        int rr = t >> 3, c8 = (t & 7) * 8;
        float4 f0 = *reinterpret_cast<const float4*>(vg + gbase + rr * HDIM + c8);
        float4 f1 = *reinterpret_cast<const float4*>(vg + gbase + rr * HDIM + c8 + 4);
        Ls[rr][c8+0] = f0.x; Ls[rr][c8+1] = f0.y; Ls[rr][c8+2] = f0.z; Ls[rr][c8+3] = f0.w;
        Ls[rr][c8+4] = f1.x; Ls[rr][c8+5] = f1.y; Ls[rr][c8+6] = f1.z; Ls[rr][c8+7] = f1.w;
    }
    __syncthreads();
    {   // V: transpose + swizzled write
        int rr = t >> 3, p = t & 7;
        int sL = p ^ (rr & 7);
        int d  = (sL >> 2) * 32 + rr;
        int j0 = (sL & 3) * 8;
        uint4v u;
        u.x = cvtpk(Ls[j0+0][d], Ls[j0+1][d]);
        u.y = cvtpk(Ls[j0+2][d], Ls[j0+3][d]);
        u.z = cvtpk(Ls[j0+4][d], Ls[j0+5][d]);
        u.w = cvtpk(Ls[j0+6][d], Ls[j0+7][d]);
        *reinterpret_cast<uint4v*>(vws + ((size_t)bh*64 + tb)*2048 + rr*64 + p*8) = u;
    }
}

// ---------- flash attention: 32x32x16, 64 q/wave, 4 waves = 2 q-waves x 2 KV-halves,
// pure-glds staging, P in regs via permlane32_swap, l via ones-MFMA ----------
__global__ __launch_bounds__(256, 2)
void attn_mfma(const float* __restrict__ qg, const u16* __restrict__ kws,
               const u16* __restrict__ vws, u16* __restrict__ og) {
    const int qB  = blockIdx.x * 128;
    const int bh  = blockIdx.y;
    const int tid = threadIdx.x;
    const int w = tid >> 6, lane = tid & 63;
    const int qw = w & 1, hf = w >> 1;
    const int r  = lane & 31;
    const int hi = lane >> 5;

    __shared__ char sh[33792];   // K 16K | V 16K | l 1K ; epilogue reuses K+V as dump

    // Q B-fragments: qb[sub][ks], col q = qB + qw*64 + sub*32 + r, k = ks*16+hi*8+i
    const float qs = 0.125f * 1.44269504088896f;
    short8 qb[2][4];
#pragma unroll
    for (int sub = 0; sub < 2; ++sub)
#pragma unroll
    for (int ks = 0; ks < 4; ++ks) {
        const float* qp = qg + ((size_t)bh * SEQ + qB + qw*64 + sub*32 + r) * HDIM + ks*16 + hi*8;
        float4 f0 = *reinterpret_cast<const float4*>(qp);
        float4 f1 = *reinterpret_cast<const float4*>(qp + 4);
        uint4v u;
        u.x = cvtpk(f0.x * qs, f0.y * qs);
        u.y = cvtpk(f0.z * qs, f0.w * qs);
        u.z = cvtpk(f1.x * qs, f1.y * qs);
        u.w = cvtpk(f1.z * qs, f1.w * qs);
        qb[sub][ks] = __builtin_bit_cast(short8, u);
    }

    const short8 ones8 = __builtin_bit_cast(short8,
        (uint4v){0x3f803f80u, 0x3f803f80u, 0x3f803f80u, 0x3f803f80u});

    // staging: thread tid handles 16B slot tid of each of 4 tiles (K h0/h1, V h0/h1)
    const u16* kbase = kws + (size_t)bh * 64 * 2048 + (size_t)tid * 8;
    const u16* vbase = vws + (size_t)bh * 64 * 2048 + (size_t)tid * 8;
    auto stage = [&](int t, int db) {
        glds16(kbase + (size_t)t * 2048,        sh + db*4096 + tid*16);
        glds16(kbase + (size_t)(32 + t) * 2048, sh + (2 + db)*4096 + tid*16);
        glds16(vbase + (size_t)t * 2048,        sh + 16384 + db*4096 + tid*16);
        glds16(vbase + (size_t)(32 + t) * 2048, sh + 16384 + (2 + db)*4096 + tid*16);
    };

    f32x16 otA0 = ZERO16, otA1 = ZERO16, otB0 = ZERO16, otB1 = ZERO16;
    f32x16 lcA = ZERO16, lcB = ZERO16;

    asm volatile("s_waitcnt vmcnt(0)" ::: "memory");
    stage(0, 0);
    stage(1, 1);
    asm volatile("s_waitcnt vmcnt(4) lgkmcnt(0)" ::: "memory");
    __builtin_amdgcn_s_barrier();

    for (int t = 0; t < NT; ++t) {
        const int db = t & 1;
        const char* Kc = sh + (hf*2 + db)*4096;
        const char* Vc = sh + 16384 + (hf*2 + db)*4096;

        // ---- QK^T (swapped): S^T[kv][q], two q-subtiles sharing each K read ----
        f32x16 stA = ZERO16, stB = ZERO16;
        __builtin_amdgcn_s_setprio(1);
#pragma unroll
        for (int ks = 0; ks < 4; ++ks) {
            short8 ka = *reinterpret_cast<const short8*>(
                Kc + r*128 + (((ks*2 + hi) ^ (r & 7)) << 4));
            stA = __builtin_amdgcn_mfma_f32_32x32x16_bf16(ka, qb[0][ks], stA, 0, 0, 0);
            stB = __builtin_amdgcn_mfma_f32_32x32x16_bf16(ka, qb[1][ks], stB, 0, 0, 0);
        }
        __builtin_amdgcn_s_setprio(0);

        // ---- unnormalized softmax: p = exp2(s), pack bf16 ----
        u32 pwA[8], pwB[8];
#pragma unroll
        for (int j = 0; j < 8; ++j) {
            pwA[j] = cvtpk(__builtin_amdgcn_exp2f(stA[2*j]), __builtin_amdgcn_exp2f(stA[2*j+1]));
            pwB[j] = cvtpk(__builtin_amdgcn_exp2f(stB[2*j]), __builtin_amdgcn_exp2f(stB[2*j+1]));
        }
        // cross-half exchange: swap(low,high) -> (word_lo, word_hi)
        plswap(pwA[0], pwA[2]); plswap(pwA[1], pwA[3]);
        plswap(pwA[4], pwA[6]); plswap(pwA[5], pwA[7]);
        plswap(pwB[0], pwB[2]); plswap(pwB[1], pwB[3]);
        plswap(pwB[4], pwB[6]); plswap(pwB[5], pwB[7]);
        short8 pbA0 = __builtin_bit_cast(short8, (uint4v){pwA[0], pwA[1], pwA[2], pwA[3]});
        short8 pbA1 = __builtin_bit_cast(short8, (uint4v){pwA[4], pwA[5], pwA[6], pwA[7]});
        short8 pbB0 = __builtin_bit_cast(short8, (uint4v){pwB[0], pwB[1], pwB[2], pwB[3]});
        short8 pbB1 = __builtin_bit_cast(short8, (uint4v){pwB[4], pwB[5], pwB[6], pwB[7]});

        // ---- PV (swapped) + l (ones-MFMA), V reads shared across subs ----
        __builtin_amdgcn_s_setprio(1);
        lcA = __builtin_amdgcn_mfma_f32_32x32x16_bf16(ones8, pbA0, lcA, 0, 0, 0);
        lcB = __builtin_amdgcn_mfma_f32_32x32x16_bf16(ones8, pbB0, lcB, 0, 0, 0);
        {
            short8 va = *reinterpret_cast<const short8*>(Vc + r*128 + (((0*4 + 0*2 + hi) ^ (r & 7)) << 4));
            otA0 = __builtin_amdgcn_mfma_f32_32x32x16_bf16(va, pbA0, otA0, 0, 0, 0);
            otB0 = __builtin_amdgcn_mfma_f32_32x32x16_bf16(va, pbB0, otB0, 0, 0, 0);
        }
        {
            short8 va = *reinterpret_cast<const short8*>(Vc + r*128 + (((1*4 + 0*2 + hi) ^ (r & 7)) << 4));
            otA1 = __builtin_amdgcn_mfma_f32_32x32x16_bf16(va, pbA0, otA1, 0, 0, 0);
            otB1 = __builtin_amdgcn_mfma_f32_32x32x16_bf16(va, pbB0, otB1, 0, 0, 0);
        }
        lcA = __builtin_amdgcn_mfma_f32_32x32x16_bf16(ones8, pbA1, lcA, 0, 0, 0);
        lcB = __builtin_amdgcn_mfma_f32_32x32x16_bf16(ones8, pbB1, lcB, 0, 0, 0);
        {
            short8 va = *reinterpret_cast<const short8*>(Vc + r*128 + (((0*4 + 1*2 + hi) ^ (r & 7)) << 4));
            otA0 = __builtin_amdgcn_mfma_f32_32x32x16_bf16(va, pbA1, otA0, 0, 0, 0);
            otB0 = __builtin_amdgcn_mfma_f32_32x32x16_bf16(va, pbB1, otB0, 0, 0, 0);
        }
        {
            short8 va = *reinterpret_cast<const short8*>(Vc + r*128 + (((1*4 + 1*2 + hi) ^ (r & 7)) << 4));
            otA1 = __builtin_amdgcn_mfma_f32_32x32x16_bf16(va, pbA1, otA1, 0, 0, 0);
            otB1 = __builtin_amdgcn_mfma_f32_32x32x16_bf16(va, pbB1, otB1, 0, 0, 0);
        }
        __builtin_amdgcn_s_setprio(0);

        // ---- bottom: drain tile t+1 loads, barrier, issue tile t+2 ----
        asm volatile("s_waitcnt vmcnt(0) lgkmcnt(0)" ::: "memory");
        __builtin_amdgcn_s_barrier();
        if (t + 2 < NT) stage(t + 2, db);
    }

    // ---- epilogue: halves combine via LDS (slot-major dump), normalize, store ----
    __syncthreads();
    char* dump = sh + qw * 16384;
    float* larea = (float*)(sh + 32768) + qw * 64;

    if (hf == 1) {
#pragma unroll
        for (int jj = 0; jj < 4; ++jj) {
            *reinterpret_cast<f32x4*>(dump + (0*4 + jj)*1024 + lane*16) =
                (f32x4){otA0[jj*4+0], otA0[jj*4+1], otA0[jj*4+2], otA0[jj*4+3]};
            *reinterpret_cast<f32x4*>(dump + (1*4 + jj)*1024 + lane*16) =
                (f32x4){otA1[jj*4+0], otA1[jj*4+1], otA1[jj*4+2], otA1[jj*4+3]};
            *reinterpret_cast<f32x4*>(dump + (2*4 + jj)*1024 + lane*16) =
                (f32x4){otB0[jj*4+0], otB0[jj*4+1], otB0[jj*4+2], otB0[jj*4+3]};
            *reinterpret_cast<f32x4*>(dump + (3*4 + jj)*1024 + lane*16) =
                (f32x4){otB1[jj*4+0], otB1[jj*4+1], otB1[jj*4+2], otB1[jj*4+3]};
        }
        larea[r]      = lcA[0];
        larea[32 + r] = lcB[0];
    }
    __syncthreads();
    if (hf == 0) {
#pragma unroll
        for (int jj = 0; jj < 4; ++jj) {
            f32x4 c0 = *reinterpret_cast<const f32x4*>(dump + (0*4 + jj)*1024 + lane*16);
            f32x4 c1 = *reinterpret_cast<const f32x4*>(dump + (1*4 + jj)*1024 + lane*16);
            f32x4 c2 = *reinterpret_cast<const f32x4*>(dump + (2*4 + jj)*1024 + lane*16);
            f32x4 c3 = *reinterpret_cast<const f32x4*>(dump + (3*4 + jj)*1024 + lane*16);
#pragma unroll
            for (int e = 0; e < 4; ++e) {
                otA0[jj*4+e] += c0[e]; otA1[jj*4+e] += c1[e];
                otB0[jj*4+e] += c2[e]; otB1[jj*4+e] += c3[e];
            }
        }
        float invA = 1.0f / (lcA[0] + larea[r]);
        float invB = 1.0f / (lcB[0] + larea[32 + r]);

        asm volatile("s_waitcnt lgkmcnt(0)" ::: "memory");
        __builtin_amdgcn_sched_barrier(0);
        // transpose-write bf16 rows (144B stride) into own dump area
        char* ta = dump;
#pragma unroll
        for (int j = 0; j < 8; ++j) {
            int dbase = ((2*j) & 3) + 8*((2*j) >> 2) + 4*hi;
            u32 wA0 = cvtpk(otA0[2*j] * invA, otA0[2*j+1] * invA);
            u32 wA1 = cvtpk(otA1[2*j] * invA, otA1[2*j+1] * invA);
            u32 wB0 = cvtpk(otB0[2*j] * invB, otB0[2*j+1] * invB);
            u32 wB1 = cvtpk(otB1[2*j] * invB, otB1[2*j+1] * invB);
            *reinterpret_cast<u32*>(ta + (0*32 + r)*144 + (0*32 + dbase)*2) = wA0;
            *reinterpret_cast<u32*>(ta + (0*32 + r)*144 + (1*32 + dbase)*2) = wA1;
            *reinterpret_cast<u32*>(ta + (1*32 + r)*144 + (0*32 + dbase)*2) = wB0;
            *reinterpret_cast<u32*>(ta + (1*32 + r)*144 + (1*32 + dbase)*2) = wB1;
        }
        asm volatile("s_waitcnt lgkmcnt(0)" ::: "memory");
        __builtin_amdgcn_sched_barrier(0);
#pragma unroll
        for (int i = 0; i < 8; ++i) {
            int idx = i * 64 + lane;
            int rr = idx >> 3, j = idx & 7;
            uint4v u = *reinterpret_cast<const uint4v*>(ta + rr*144 + j*16);
            *reinterpret_cast<uint4v*>(
                og + ((size_t)bh * SEQ + qB + qw*64 + rr) * HDIM + j*8) = u;
        }
    }
}

// ---------- projection: C = X(bf16) @ W^T + bias via MFMA ----------
__global__ __launch_bounds__(256)
void proj_mfma(const u16* __restrict__ X, const float* __restrict__ Wg,
               const float* __restrict__ bias, float* __restrict__ out) {
    const int g0 = blockIdx.x * 128;
    const int n0 = blockIdx.y * 64;
    const int tid = threadIdx.x;
    const int w = tid >> 6, lane = tid & 63;
    const int c = lane & 15, gq = lane >> 4;
    const int cx = c & 7;

    __shared__ char sh[49152];
    u16* const XbA = (u16*)(sh);
    u16* const XbB = (u16*)(sh + 16384);
    u16* const WbA = (u16*)(sh + 32768);
    u16* const WbB = (u16*)(sh + 40960);

    const int wn0 = tid >> 3, wp = tid & 7;

    f32x4 acc[2][4];
#pragma unroll
    for (int mt = 0; mt < 2; ++mt)
#pragma unroll
    for (int nt = 0; nt < 4; ++nt) acc[mt][nt] = (f32x4){0.f,0.f,0.f,0.f};

    float4 w0a, w0b, w1a, w1b;

    auto loadW = [&](int kt) {
        const float* p0 = Wg + (size_t)(n0 + wn0) * DCAT + kt*64 + ((wp ^ (wn0 & 7)) * 8);
        const float* p1 = Wg + (size_t)(n0 + 32 + wn0) * DCAT + kt*64 + ((wp ^ ((32 + wn0) & 7)) * 8);
        w0a = *reinterpret_cast<const float4*>(p0);
        w0b = *reinterpret_cast<const float4*>(p0 + 4);
        w1a = *reinterpret_cast<const float4*>(p1);
        w1b = *reinterpret_cast<const float4*>(p1 + 4);
    };
    auto writeW = [&](u16* Wb) {
        uint4v u;
        u.x = cvtpk(w0a.x, w0a.y); u.y = cvtpk(w0a.z, w0a.w);
        u.z = cvtpk(w0b.x, w0b.y); u.w = cvtpk(w0b.z, w0b.w);
        *reinterpret_cast<uint4v*>((char*)Wb + wn0*128 + wp*16) = u;
        u.x = cvtpk(w1a.x, w1a.y); u.y = cvtpk(w1a.z, w1a.w);
        u.z = cvtpk(w1b.x, w1b.y); u.w = cvtpk(w1b.z, w1b.w);
        *reinterpret_cast<uint4v*>((char*)Wb + (32 + wn0)*128 + wp*16) = u;
    };
    auto issueX = [&](int kt, u16* Xb) {
#pragma unroll
        for (int i = 0; i < 4; ++i) {
            int s = w*256 + i*64 + lane;
            int rr = s >> 3, p = s & 7;
            glds16(X + (size_t)(g0 + rr) * DCAT + kt*64 + ((p ^ (rr & 7)) * 8),
                   (char*)Xb + w*4096 + i*1024);
        }
    };

    loadW(0);
    issueX(0, XbA);
    writeW(WbA);
    loadW(1);
    issueX(1, XbB);
    asm volatile("s_waitcnt vmcnt(8) lgkmcnt(0)" ::: "memory");
    __builtin_amdgcn_s_barrier();

    for (int kt = 0; kt < 8; ++kt) {
        u16* const Xc = (kt & 1) ? XbB : XbA;
        u16* const Wc = (kt & 1) ? WbB : WbA;
        u16* const Wn = (kt & 1) ? WbA : WbB;

        __builtin_amdgcn_s_setprio(1);
#pragma unroll
        for (int ks = 0; ks < 2; ++ks) {
            short8 a0 = *reinterpret_cast<const short8*>(
                (char*)Xc + (w*32 + c)*128 + (((ks*4 + gq) ^ cx) << 4));
            short8 a1 = *reinterpret_cast<const short8*>(
                (char*)Xc + (w*32 + 16 + c)*128 + (((ks*4 + gq) ^ cx) << 4));
#pragma unroll
            for (int nt = 0; nt < 4; ++nt) {
                short8 bb = *reinterpret_cast<const short8*>(
                    (char*)Wc + (nt*16 + c)*128 + (((ks*4 + gq) ^ cx) << 4));
                acc[0][nt] = __builtin_amdgcn_mfma_f32_16x16x32_bf16(a0, bb, acc[0][nt], 0,0,0);
                acc[1][nt] = __builtin_amdgcn_mfma_f32_16x16x32_bf16(a1, bb, acc[1][nt], 0,0,0);
            }
        }
        __builtin_amdgcn_s_setprio(0);

        if (kt + 1 < 8) writeW(Wn);
        if (kt + 2 < 8) loadW(kt + 2);
        if (kt < 6)
            asm volatile("s_waitcnt vmcnt(4) lgkmcnt(0)" ::: "memory");
        else
            asm volatile("s_waitcnt vmcnt(0) lgkmcnt(0)" ::: "memory");
        __builtin_amdgcn_s_barrier();
        if (kt + 2 < 8) issueX(kt + 2, Xc);
    }

    float bv[4];
#pragma unroll
    for (int nt = 0; nt < 4; ++nt) bv[nt] = bias[n0 + nt*16 + c];
#pragma unroll
    for (int mt = 0; mt < 2; ++mt)
#pragma unroll
    for (int nt = 0; nt < 4; ++nt)
#pragma unroll
    for (int rr = 0; rr < 4; ++rr)
        out[(size_t)(g0 + w*32 + mt*16 + gq*4 + rr) * DIN + n0 + nt*16 + c] =
            acc[mt][nt][rr] + bv[nt];
}

extern "C" void kernel_launch(void* const* d_in, const int* in_sizes, int n_in,
                              void* d_out, int out_size, void* d_ws, size_t ws_size,
                              hipStream_t stream) {
    (void)in_sizes; (void)n_in; (void)out_size; (void)ws_size;
    const float* q    = (const float*)d_in[0];
    const float* k    = (const float*)d_in[1];
    const float* v    = (const float*)d_in[2];
    const float* W    = (const float*)d_in[3];
    const float* bias = (const float*)d_in[4];

    // K bf16 tiles live in d_out's first 8MB (proj fully overwrites d_out afterwards).
    u16* kws = (u16*)d_out;
    u16* vws = (u16*)d_ws;                              // 8 MB
    u16* ob  = vws + (size_t)NBH * 64 * 2048;           // 8 MB

    kv_prepass<<<dim3(64, NBH), 256, 0, stream>>>(k, v, kws, vws);
    attn_mfma <<<dim3(16, NBH), 256, 0, stream>>>(q, kws, vws, ob);
    proj_mfma <<<dim3((BATCH*SEQ)/128, DIN/64), 256, 0, stream>>>(ob, W, bias, (float*)d_out);
}